// Round 2
// baseline (221.825 us; speedup 1.0000x reference)
//
#include <hip/hip_runtime.h>
#include <hip/hip_bf16.h>
#include <math.h>

#define B_  256
#define T_  512
#define D_  256
#define A_  50
#define EPS 1e-7f
#define NW  16   // waves per block (R11: back to 16 — occupancy is the lever)

typedef short  short8  __attribute__((ext_vector_type(8)));
typedef float  floatx4 __attribute__((ext_vector_type(4)));

__device__ inline unsigned short f2bf(float f) {
    unsigned int u = __float_as_uint(f);
    u = (u + 0x7fffu + ((u >> 16) & 1u)) >> 16;   // RNE (inputs are finite)
    return (unsigned short)u;
}

// ---------------------------------------------------------------------------
// Prep: swizzle W [256][50] fp32 into bf16 B-fragment order for
// mfma_f32_16x16x32_bf16, zero-padded to N=64. Fragment (nt,ks), lane l,
// element j holds B[k][n] with n = nt*16 + (l&15), k = ks*32 + (l>>4)*8 + j.
// Layout: Wf[((nt*8+ks)*64 + l)*8 + j]. Also bias/u zero-padded to 64.
// (unchanged)
// ---------------------------------------------------------------------------
__global__ void prep_kernel(const float* __restrict__ W,
                            const float* __restrict__ bias,
                            const float* __restrict__ u,
                            unsigned short* __restrict__ Wf,
                            float* __restrict__ bu64)
{
    int idx = blockIdx.x * 256 + threadIdx.x;      // 0 .. 16383
    int j  = idx & 7;
    int l  = (idx >> 3) & 63;
    int ks = (idx >> 9) & 7;
    int nt = idx >> 12;
    int n  = nt * 16 + (l & 15);
    int k  = ks * 32 + (l >> 4) * 8 + j;
    float val = (n < A_) ? W[k * A_ + n] : 0.0f;
    Wf[idx] = f2bf(val);
    if (idx < 64) {
        bu64[idx]      = (idx < A_) ? bias[idx] : 0.0f;
        bu64[64 + idx] = (idx < A_) ? u[idx]    : 0.0f;
    }
}

// pack 4 floats -> 4 bf16 (hardware v_cvt_pk_bf16_f32, RNE)
__device__ inline void pack_bf4(short8& av, int base, float fx, float fy,
                                float fz, float fw)
{
    union { __hip_bfloat162 h2; int i; } c0, c1;
    c0.h2 = __float22bfloat162_rn(make_float2(fx, fy));
    c1.h2 = __float22bfloat162_rn(make_float2(fz, fw));
    av[base + 0] = (short)(c0.i & 0xffff);
    av[base + 1] = (short)((unsigned)c0.i >> 16);
    av[base + 2] = (short)(c1.i & 0xffff);
    av[base + 3] = (short)((unsigned)c1.i >> 16);
}

__device__ inline float4 shflxor4(float4 v, int m) {
    return make_float4(__shfl_xor(v.x, m), __shfl_xor(v.y, m),
                       __shfl_xor(v.z, m), __shfl_xor(v.w, m));
}
__device__ inline float4 add4(float4 a, float4 b) {
    return make_float4(a.x + b.x, a.y + b.y, a.z + b.z, a.w + b.w);
}
__device__ inline float4 sel4(bool p, float4 a, float4 b) {   // p ? a : b
    return make_float4(p ? a.x : b.x, p ? a.y : b.y,
                       p ? a.z : b.z, p ? a.w : b.w);
}

// ---------------------------------------------------------------------------
// R11: high-occupancy single-pass. One block per batch, 1024 threads
// (16 waves, 4 waves/SIMD at <=128 VGPR).
//
// R10 post-mortem: pre[2][16]+acc2[16] needed ~220 VGPRs against a 128
// budget -> partial scratch spill (WRITE_SIZE 33 MB vs 0.26 MB output) ->
// every tile serialized on scratch+HBM latency (1.5 TB/s, occ 18%).
//
// R11 fixes the register economy instead of fighting the allocator:
//  - single-buffered pre[16] (64 VGPRs), no register double-buffer;
//  - pooling accumulator shrunk 64 -> 4 VGPRs: each tile's weighted
//    vectors (pre[i]*e_row) are reduced over the 16 c-lanes IMMEDIATELY
//    via 4-step recursive halving (cndmask keep/send + shfl_xor masks
//    8/4/2/1, all compile-time register indices). Lane (c,quad) ends up
//    owning granule g=(c>>1)*8+quad*2+(c&1) (bijective over 64 lanes),
//    one float4 accumulated across its 2 tiles.
//  Peak ~110 VGPR -> 16 waves/CU resident; latency hiding by TLP
//  (the m13 copy kernel hits 6.3 TB/s this way, no prefetch games).
// ---------------------------------------------------------------------------
__global__ __launch_bounds__(1024)
__attribute__((amdgpu_waves_per_eu(4)))
void fused_kernel(const float* __restrict__ x,
                  const unsigned short* __restrict__ Wf,
                  const float* __restrict__ bu64,
                  float* __restrict__ out)
{
    __shared__ int4  Wl[2048];         // 32 KB: Wf staged, fragment order
    __shared__ float s_lds[T_];        // 2 KB: exp-scores
    __shared__ float part[NW * 256];   // 16 KB: per-wave pooled partials
    __shared__ float s_inv;

    const int tid  = threadIdx.x;
    const int w    = tid >> 6;      // 0..15
    const int l    = tid & 63;
    const int c    = l & 15;        // A-col / time-row-owner within tile
    const int quad = l >> 4;        // k-slice / C-row-group
    const int bb   = blockIdx.x;

    // Stage Wf -> LDS (32 KB, coalesced int4; B-reads then live on lgkmcnt,
    // so the vmcnt queue holds ONLY the HBM x-loads)
    {
        const int4* __restrict__ wsrc = (const int4*)Wf;
        Wl[tid]        = wsrc[tid];
        Wl[tid + 1024] = wsrc[tid + 1024];
    }

    const float*  __restrict__ xb  = x + (size_t)bb * T_ * D_;
    const short8* __restrict__ wl8 = (const short8*)Wl;

    float bnc[4], unc[4];
    #pragma unroll
    for (int nt = 0; nt < 4; nt++) {
        bnc[nt] = bu64[nt * 16 + c];
        unc[nt] = bu64[64 + nt * 16 + c];
    }
    __syncthreads();   // Wl ready

    float4 accp = make_float4(0.f, 0.f, 0.f, 0.f);  // this lane's granule

    // ---- 2 tiles of 16 rows per wave: rows [w*32, w*32+32) ----
    #pragma unroll
    for (int t = 0; t < 2; t++) {
        const int rowbase = w * 32 + t * 16;
        const float4* __restrict__ xr =
            (const float4*)(xb + (size_t)(rowbase + c) * D_);

        // 16 independent HBM loads (16 KB/wave in flight, single-buffered)
        float4 pre[16];
        #pragma unroll
        for (int i = 0; i < 16; i++)
            pre[i] = xr[(i >> 1) * 8 + quad * 2 + (i & 1)];

        floatx4 acc[4];
        #pragma unroll
        for (int nt = 0; nt < 4; nt++) acc[nt] = (floatx4){0.f, 0.f, 0.f, 0.f};

        #pragma unroll
        for (int ks = 0; ks < 8; ks++) {
            const float4 a0 = pre[2 * ks];
            const float4 a1 = pre[2 * ks + 1];
            short8 av;
            pack_bf4(av, 0, a0.x, a0.y, a0.z, a0.w);
            pack_bf4(av, 4, a1.x, a1.y, a1.z, a1.w);
            #pragma unroll
            for (int nt = 0; nt < 4; nt++) {
                const short8 bv = wl8[(nt * 8 + ks) * 64 + l];  // ds_read_b128
                acc[nt] = __builtin_amdgcn_mfma_f32_16x16x32_bf16(av, bv, acc[nt], 0, 0, 0);
            }
        }

        // scores for this wave's 16 rows (C layout: col=c, row=quad*4+r)
        #pragma unroll
        for (int r = 0; r < 4; r++) {
            float v = 0.0f;
            #pragma unroll
            for (int nt = 0; nt < 4; nt++)
                v += tanhf(acc[nt][r] + bnc[nt]) * unc[nt];
            #pragma unroll
            for (int off = 1; off < 16; off <<= 1)
                v += __shfl_xor(v, off, 16);
            if (c == 0)
                s_lds[rowbase + quad * 4 + r] = expf(v);
        }

        // weight = exp-score of THIS lane's row (same-wave LDS RAW, in-order)
        const float ec = s_lds[rowbase + c];

        // weighted vectors, then recursive halving over the 16 c-lanes:
        // after masks 8/4/2/1, lane c holds the row-sum for its index i=c.
        float4 v16[16];
        #pragma unroll
        for (int i = 0; i < 16; i++)
            v16[i] = make_float4(pre[i].x * ec, pre[i].y * ec,
                                 pre[i].z * ec, pre[i].w * ec);

        float4 h8[8];
        #pragma unroll
        for (int j = 0; j < 8; j++) {
            const float4 a = v16[j], b = v16[j + 8];
            h8[j] = add4(sel4((c & 8) != 0, b, a),
                         shflxor4(sel4((c & 8) != 0, a, b), 8));
        }
        float4 h4[4];
        #pragma unroll
        for (int j = 0; j < 4; j++) {
            const float4 a = h8[j], b = h8[j + 4];
            h4[j] = add4(sel4((c & 4) != 0, b, a),
                         shflxor4(sel4((c & 4) != 0, a, b), 4));
        }
        float4 h2[2];
        #pragma unroll
        for (int j = 0; j < 2; j++) {
            const float4 a = h4[j], b = h4[j + 2];
            h2[j] = add4(sel4((c & 2) != 0, b, a),
                         shflxor4(sel4((c & 2) != 0, a, b), 2));
        }
        {
            const float4 a = h2[0], b = h2[1];
            const float4 h1 = add4(sel4((c & 1) != 0, b, a),
                                   shflxor4(sel4((c & 1) != 0, a, b), 1));
            accp = add4(accp, h1);
        }
    }

    // lane (c,quad) owns granule g -> bijective float4 store, no masking
    const int g = (c >> 1) * 8 + quad * 2 + (c & 1);
    *(float4*)&part[w * 256 + g * 4] = accp;
    __syncthreads();   // all partials + all s_lds scores visible

    // ---- denominator: wave 0 sums the 512 exp-scores ----
    if (tid < 64) {
        float s = 0.0f;
        #pragma unroll
        for (int k = 0; k < 8; k++) s += s_lds[tid + k * 64];
        #pragma unroll
        for (int off = 1; off < 64; off <<= 1) s += __shfl_xor(s, off);
        if (tid == 0) s_inv = 1.0f / (s + EPS);
    }
    __syncthreads();

    // ---- final: sum the 16 wave partials, scale, store ----
    if (tid < 256) {
        float o = 0.0f;
        #pragma unroll
        for (int wv = 0; wv < NW; wv++) o += part[wv * 256 + tid];
        out[(size_t)bb * 256 + tid] = o * s_inv;
    }
}

// ---------------------------------------------------------------------------
extern "C" void kernel_launch(void* const* d_in, const int* in_sizes, int n_in,
                              void* d_out, int out_size, void* d_ws, size_t ws_size,
                              hipStream_t stream)
{
    const float* x = (const float*)d_in[0];
    const float* W = (const float*)d_in[1];
    const float* b = (const float*)d_in[2];
    const float* u = (const float*)d_in[3];

    unsigned short* Wf  = (unsigned short*)d_ws;          // 16384 u16
    float*         bu64 = (float*)(Wf + 16384);           // 128 f
    float*         out  = (float*)d_out;

    prep_kernel  <<<64,  256,  0, stream>>>(W, b, u, Wf, bu64);
    fused_kernel <<<B_,  1024, 0, stream>>>(x, Wf, bu64, out);
}

// Round 6
// 220.401 us; speedup vs baseline: 1.0065x; 1.0065x over previous
//
#include <hip/hip_runtime.h>
#include <hip/hip_bf16.h>
#include <math.h>

#define B_  256
#define T_  512
#define D_  256
#define A_  50
#define EPS 1e-7f
#define NW  16   // waves per block

typedef short  short8  __attribute__((ext_vector_type(8)));
typedef float  floatx4 __attribute__((ext_vector_type(4)));

__device__ inline unsigned short f2bf(float f) {
    unsigned int u = __float_as_uint(f);
    u = (u + 0x7fffu + ((u >> 16) & 1u)) >> 16;   // RNE (inputs are finite)
    return (unsigned short)u;
}

// ---------------------------------------------------------------------------
// Prep: swizzle W [256][50] fp32 into bf16 B-fragment order for
// mfma_f32_16x16x32_bf16, zero-padded to N=64. Fragment (nt,ks), lane l,
// element j holds B[k][n] with n = nt*16 + (l&15), k = ks*32 + (l>>4)*8 + j.
// Layout: Wf[((nt*8+ks)*64 + l)*8 + j]. Also bias/u zero-padded to 64.
// (unchanged)
// ---------------------------------------------------------------------------
__global__ void prep_kernel(const float* __restrict__ W,
                            const float* __restrict__ bias,
                            const float* __restrict__ u,
                            unsigned short* __restrict__ Wf,
                            float* __restrict__ bu64)
{
    int idx = blockIdx.x * 256 + threadIdx.x;      // 0 .. 16383
    int j  = idx & 7;
    int l  = (idx >> 3) & 63;
    int ks = (idx >> 9) & 7;
    int nt = idx >> 12;
    int n  = nt * 16 + (l & 15);
    int k  = ks * 32 + (l >> 4) * 8 + j;
    float val = (n < A_) ? W[k * A_ + n] : 0.0f;
    Wf[idx] = f2bf(val);
    if (idx < 64) {
        bu64[idx]      = (idx < A_) ? bias[idx] : 0.0f;
        bu64[64 + idx] = (idx < A_) ? u[idx]    : 0.0f;
    }
}

// pack 4 floats -> 4 bf16 (hardware v_cvt_pk_bf16_f32, RNE)
__device__ inline void pack_bf4(short8& av, int base, float fx, float fy,
                                float fz, float fw)
{
    union { __hip_bfloat162 h2; int i; } c0, c1;
    c0.h2 = __float22bfloat162_rn(make_float2(fx, fy));
    c1.h2 = __float22bfloat162_rn(make_float2(fz, fw));
    av[base + 0] = (short)(c0.i & 0xffff);
    av[base + 1] = (short)((unsigned)c0.i >> 16);
    av[base + 2] = (short)(c1.i & 0xffff);
    av[base + 3] = (short)((unsigned)c1.i >> 16);
}

__device__ inline float4 shflxor4(float4 v, int m) {
    return make_float4(__shfl_xor(v.x, m), __shfl_xor(v.y, m),
                       __shfl_xor(v.z, m), __shfl_xor(v.w, m));
}
__device__ inline float4 add4(float4 a, float4 b) {
    return make_float4(a.x + b.x, a.y + b.y, a.z + b.z, a.w + b.w);
}
__device__ inline float4 sel4(bool p, float4 a, float4 b) {   // p ? a : b
    return make_float4(p ? a.x : b.x, p ? a.y : b.y,
                       p ? a.z : b.z, p ? a.w : b.w);
}
__device__ inline float4 mul4s(float4 a, float s) {
    return make_float4(a.x * s, a.y * s, a.z * s, a.w * s);
}

// ---------------------------------------------------------------------------
// R15: revert to the R11 compute structure (the last one that PASSED, at
// absmax 2^-10 exactly) and fix its ONE measured defect: the spill.
//
// R12/R14 post-mortem: the LDS-staged pipeline failed DETERMINISTICALLY
// (JSON absmax 468.0 in both, pytest 7e-3/1e-2) with both async and sync
// staging, while every index mapping audits clean — unexplained, so the
// architecture is abandoned per methodology.
//
// R11's defect per counters: waves_per_eu(4) is a MIN only -> allocator
// targeted 8 waves/EU -> 64-VGPR clamp -> pre[16]+v16[16] spilled
// (WRITE_SIZE 26.9 MB vs 0.26 MB output, 1.37 TB/s, occ 18%).
// R15 deltas (register economy only, ZERO numerics changes):
//  1. waves_per_eu(4,4): forces the 128-VGPR budget (respected in R10/R14).
//  2. v16[16] temp array deleted — the *ec weighting is folded into the
//     first butterfly halving step (same values, same order -> bitwise
//     identical to R11). Peak live ~110 VGPR < 128.
// Latency hiding is pure TLP: 16 waves/CU, 16 indep 16B loads per wave.
// ---------------------------------------------------------------------------
__global__ __launch_bounds__(1024)
__attribute__((amdgpu_waves_per_eu(4, 4)))
void fused_kernel(const float* __restrict__ x,
                  const unsigned short* __restrict__ Wf,
                  const float* __restrict__ bu64,
                  float* __restrict__ out)
{
    __shared__ int4  Wl[2048];         // 32 KB: Wf staged, fragment order
    __shared__ float s_lds[T_];        // 2 KB: exp-scores
    __shared__ float part[NW * 256];   // 16 KB: per-wave pooled partials
    __shared__ float s_inv;

    const int tid  = threadIdx.x;
    const int w    = tid >> 6;      // 0..15
    const int l    = tid & 63;
    const int c    = l & 15;        // A-col / time-row-owner within tile
    const int quad = l >> 4;        // k-slice / C-row-group
    const int bb   = blockIdx.x;

    // Stage Wf -> LDS (32 KB, coalesced int4; B-reads then live on lgkmcnt)
    {
        const int4* __restrict__ wsrc = (const int4*)Wf;
        Wl[tid]        = wsrc[tid];
        Wl[tid + 1024] = wsrc[tid + 1024];
    }

    const float*  __restrict__ xb  = x + (size_t)bb * T_ * D_;
    const short8* __restrict__ wl8 = (const short8*)Wl;

    float bnc[4], unc[4];
    #pragma unroll
    for (int nt = 0; nt < 4; nt++) {
        bnc[nt] = bu64[nt * 16 + c];
        unc[nt] = bu64[64 + nt * 16 + c];
    }
    __syncthreads();   // Wl ready

    float4 accp = make_float4(0.f, 0.f, 0.f, 0.f);  // this lane's granule

    // ---- 2 tiles of 16 rows per wave: rows [w*32, w*32+32) ----
    #pragma unroll
    for (int t = 0; t < 2; t++) {
        const int rowbase = w * 32 + t * 16;
        const float4* __restrict__ xr =
            (const float4*)(xb + (size_t)(rowbase + c) * D_);

        // 16 independent HBM loads (16 KB/wave in flight, single-buffered)
        float4 pre[16];
        #pragma unroll
        for (int i = 0; i < 16; i++)
            pre[i] = xr[(i >> 1) * 8 + quad * 2 + (i & 1)];

        floatx4 acc[4];
        #pragma unroll
        for (int nt = 0; nt < 4; nt++) acc[nt] = (floatx4){0.f, 0.f, 0.f, 0.f};

        #pragma unroll
        for (int ks = 0; ks < 8; ks++) {
            const float4 a0 = pre[2 * ks];
            const float4 a1 = pre[2 * ks + 1];
            short8 av;
            pack_bf4(av, 0, a0.x, a0.y, a0.z, a0.w);
            pack_bf4(av, 4, a1.x, a1.y, a1.z, a1.w);
            #pragma unroll
            for (int nt = 0; nt < 4; nt++) {
                const short8 bv = wl8[(nt * 8 + ks) * 64 + l];  // ds_read_b128
                acc[nt] = __builtin_amdgcn_mfma_f32_16x16x32_bf16(av, bv, acc[nt], 0, 0, 0);
            }
        }

        // scores for this wave's 16 rows (C layout: col=c, row=quad*4+r)
        #pragma unroll
        for (int r = 0; r < 4; r++) {
            float v = 0.0f;
            #pragma unroll
            for (int nt = 0; nt < 4; nt++)
                v += tanhf(acc[nt][r] + bnc[nt]) * unc[nt];
            #pragma unroll
            for (int off = 1; off < 16; off <<= 1)
                v += __shfl_xor(v, off, 16);
            if (c == 0)
                s_lds[rowbase + quad * 4 + r] = expf(v);
        }

        // weight = exp-score of THIS lane's row (same-wave LDS RAW, in-order)
        const float ec = s_lds[rowbase + c];

        // recursive halving over the 16 c-lanes; *ec folded into step 1
        // (identical arithmetic/order to R11's v16[] version — bitwise same).
        float4 h8[8];
        #pragma unroll
        for (int j = 0; j < 8; j++) {
            const float4 a = mul4s(pre[j], ec);
            const float4 b = mul4s(pre[j + 8], ec);
            h8[j] = add4(sel4((c & 8) != 0, b, a),
                         shflxor4(sel4((c & 8) != 0, a, b), 8));
        }
        float4 h4[4];
        #pragma unroll
        for (int j = 0; j < 4; j++) {
            const float4 a = h8[j], b = h8[j + 4];
            h4[j] = add4(sel4((c & 4) != 0, b, a),
                         shflxor4(sel4((c & 4) != 0, a, b), 4));
        }
        float4 h2[2];
        #pragma unroll
        for (int j = 0; j < 2; j++) {
            const float4 a = h4[j], b = h4[j + 2];
            h2[j] = add4(sel4((c & 2) != 0, b, a),
                         shflxor4(sel4((c & 2) != 0, a, b), 2));
        }
        {
            const float4 a = h2[0], b = h2[1];
            const float4 h1 = add4(sel4((c & 1) != 0, b, a),
                                   shflxor4(sel4((c & 1) != 0, a, b), 1));
            accp = add4(accp, h1);
        }
    }

    // lane (c,quad) owns granule g -> bijective float4 store, no masking
    const int g = (c >> 1) * 8 + quad * 2 + (c & 1);
    *(float4*)&part[w * 256 + g * 4] = accp;
    __syncthreads();   // all partials + all s_lds scores visible

    // ---- denominator: wave 0 sums the 512 exp-scores ----
    if (tid < 64) {
        float s = 0.0f;
        #pragma unroll
        for (int k = 0; k < 8; k++) s += s_lds[tid + k * 64];
        #pragma unroll
        for (int off = 1; off < 64; off <<= 1) s += __shfl_xor(s, off);
        if (tid == 0) s_inv = 1.0f / (s + EPS);
    }
    __syncthreads();

    // ---- final: sum the 16 wave partials, scale, store ----
    if (tid < 256) {
        float o = 0.0f;
        #pragma unroll
        for (int wv = 0; wv < NW; wv++) o += part[wv * 256 + tid];
        out[(size_t)bb * 256 + tid] = o * s_inv;
    }
}

// ---------------------------------------------------------------------------
extern "C" void kernel_launch(void* const* d_in, const int* in_sizes, int n_in,
                              void* d_out, int out_size, void* d_ws, size_t ws_size,
                              hipStream_t stream)
{
    const float* x = (const float*)d_in[0];
    const float* W = (const float*)d_in[1];
    const float* b = (const float*)d_in[2];
    const float* u = (const float*)d_in[3];

    unsigned short* Wf  = (unsigned short*)d_ws;          // 16384 u16
    float*         bu64 = (float*)(Wf + 16384);           // 128 f
    float*         out  = (float*)d_out;

    prep_kernel  <<<64,  256,  0, stream>>>(W, b, u, Wf, bu64);
    fused_kernel <<<B_,  1024, 0, stream>>>(x, Wf, bu64, out);
}

// Round 7
// 206.698 us; speedup vs baseline: 1.0732x; 1.0663x over previous
//
#include <hip/hip_runtime.h>
#include <hip/hip_bf16.h>
#include <math.h>

#define B_  256
#define T_  512
#define D_  256
#define A_  50
#define EPS 1e-7f
#define NW  16   // waves per block

typedef short  short8  __attribute__((ext_vector_type(8)));
typedef float  floatx4 __attribute__((ext_vector_type(4)));

__device__ inline unsigned short f2bf(float f) {
    unsigned int u = __float_as_uint(f);
    u = (u + 0x7fffu + ((u >> 16) & 1u)) >> 16;   // RNE (inputs are finite)
    return (unsigned short)u;
}

// ---------------------------------------------------------------------------
// Prep: swizzle W [256][50] fp32 into bf16 B-fragment order for
// mfma_f32_16x16x32_bf16, zero-padded to N=64. Fragment (nt,ks), lane l,
// element j holds B[k][n] with n = nt*16 + (l&15), k = ks*32 + (l>>4)*8 + j.
// Layout: Wf[((nt*8+ks)*64 + l)*8 + j]. Also bias/u zero-padded to 64.
// (unchanged)
// ---------------------------------------------------------------------------
__global__ void prep_kernel(const float* __restrict__ W,
                            const float* __restrict__ bias,
                            const float* __restrict__ u,
                            unsigned short* __restrict__ Wf,
                            float* __restrict__ bu64)
{
    int idx = blockIdx.x * 256 + threadIdx.x;      // 0 .. 16383
    int j  = idx & 7;
    int l  = (idx >> 3) & 63;
    int ks = (idx >> 9) & 7;
    int nt = idx >> 12;
    int n  = nt * 16 + (l & 15);
    int k  = ks * 32 + (l >> 4) * 8 + j;
    float val = (n < A_) ? W[k * A_ + n] : 0.0f;
    Wf[idx] = f2bf(val);
    if (idx < 64) {
        bu64[idx]      = (idx < A_) ? bias[idx] : 0.0f;
        bu64[64 + idx] = (idx < A_) ? u[idx]    : 0.0f;
    }
}

// pack 4 floats -> 4 bf16 (hardware v_cvt_pk_bf16_f32, RNE)
__device__ inline void pack_bf4(short8& av, int base, float fx, float fy,
                                float fz, float fw)
{
    union { __hip_bfloat162 h2; int i; } c0, c1;
    c0.h2 = __float22bfloat162_rn(make_float2(fx, fy));
    c1.h2 = __float22bfloat162_rn(make_float2(fz, fw));
    av[base + 0] = (short)(c0.i & 0xffff);
    av[base + 1] = (short)((unsigned)c0.i >> 16);
    av[base + 2] = (short)(c1.i & 0xffff);
    av[base + 3] = (short)((unsigned)c1.i >> 16);
}

__device__ inline float4 shflxor4(float4 v, int m) {
    return make_float4(__shfl_xor(v.x, m), __shfl_xor(v.y, m),
                       __shfl_xor(v.z, m), __shfl_xor(v.w, m));
}
__device__ inline float4 add4(float4 a, float4 b) {
    return make_float4(a.x + b.x, a.y + b.y, a.z + b.z, a.w + b.w);
}
__device__ inline float4 sel4(bool p, float4 a, float4 b) {   // p ? a : b
    return make_float4(p ? a.x : b.x, p ? a.y : b.y,
                       p ? a.z : b.z, p ? a.w : b.w);
}
__device__ inline float4 mul4s(float4 a, float s) {
    return make_float4(a.x * s, a.y * s, a.z * s, a.w * s);
}

// ---------------------------------------------------------------------------
// R16: fit the 64-VGPR reality instead of fighting it.
//
// Evidence R9/R11/R15: with MFMA present, the allocator leaves 64 arch
// VGPRs no matter what waves_per_eu asks (R15: (4,4) -> still 64 + 37 MB
// scratch writes). So the algorithm is restructured to need ~50 live:
//  1. Score phase STREAMS x: per k-step, load the lane's 2 float4
//     A-fragment granules, pack to bf16, 4 MFMAs, values die. No pre[16].
//  2. Pool phase RE-LOADS the same 16 float4s (identical addresses, L1/L2
//     hot — R7/R9 proved x re-reads are cache-absorbed, zero extra HBM)
//     and feeds them pair-wise into the first butterfly halving level.
//     Peak live ~ h8[8] (32 VGPR) + pending loads.
// Butterfly / score math identical values+order to R15 (passed, 2^-10).
// At ~50 VGPR: no spill, 8 waves/EU, 2 blocks/CU (LDS 50 KB), 32 waves/CU
// -> pure-TLP latency hiding (the m13 6.3 TB/s mechanism).
// ---------------------------------------------------------------------------
__global__ __launch_bounds__(1024)
void fused_kernel(const float* __restrict__ x,
                  const unsigned short* __restrict__ Wf,
                  const float* __restrict__ bu64,
                  float* __restrict__ out)
{
    __shared__ int4  Wl[2048];         // 32 KB: Wf staged, fragment order
    __shared__ float s_lds[T_];        // 2 KB: exp-scores
    __shared__ float part[NW * 256];   // 16 KB: per-wave pooled partials
    __shared__ float s_inv;

    const int tid  = threadIdx.x;
    const int w    = tid >> 6;      // 0..15
    const int l    = tid & 63;
    const int c    = l & 15;        // A-row owner within 16-row tile
    const int quad = l >> 4;        // k-slice / C-row-group
    const int bb   = blockIdx.x;

    // Stage Wf -> LDS (32 KB, coalesced int4; B-reads live on lgkmcnt)
    {
        const int4* __restrict__ wsrc = (const int4*)Wf;
        Wl[tid]        = wsrc[tid];
        Wl[tid + 1024] = wsrc[tid + 1024];
    }

    const float*  __restrict__ xb  = x + (size_t)bb * T_ * D_;
    const short8* __restrict__ wl8 = (const short8*)Wl;

    float bnc[4], unc[4];
    #pragma unroll
    for (int nt = 0; nt < 4; nt++) {
        bnc[nt] = bu64[nt * 16 + c];
        unc[nt] = bu64[64 + nt * 16 + c];
    }
    __syncthreads();   // Wl ready

    float4 accp = make_float4(0.f, 0.f, 0.f, 0.f);  // this lane's granule

    // ---- 2 tiles of 16 rows per wave: rows [w*32, w*32+32) ----
    #pragma unroll
    for (int t = 0; t < 2; t++) {
        const int rowbase = w * 32 + t * 16;
        const float4* __restrict__ xr =
            (const float4*)(xb + (size_t)(rowbase + c) * D_);

        floatx4 acc[4];
        #pragma unroll
        for (int nt = 0; nt < 4; nt++) acc[nt] = (floatx4){0.f, 0.f, 0.f, 0.f};

        // ---- score phase: stream 2 granules per k-step (no pre[] array) ----
        #pragma unroll
        for (int ks = 0; ks < 8; ks++) {
            const float4 a0 = xr[8 * ks + 2 * quad];
            const float4 a1 = xr[8 * ks + 2 * quad + 1];
            short8 av;
            pack_bf4(av, 0, a0.x, a0.y, a0.z, a0.w);
            pack_bf4(av, 4, a1.x, a1.y, a1.z, a1.w);
            #pragma unroll
            for (int nt = 0; nt < 4; nt++) {
                const short8 bv = wl8[(nt * 8 + ks) * 64 + l];  // ds_read_b128
                acc[nt] = __builtin_amdgcn_mfma_f32_16x16x32_bf16(av, bv, acc[nt], 0, 0, 0);
            }
        }

        // scores for this wave's 16 rows (C layout: col=c, row=quad*4+r)
        #pragma unroll
        for (int r = 0; r < 4; r++) {
            float v = 0.0f;
            #pragma unroll
            for (int nt = 0; nt < 4; nt++)
                v += tanhf(acc[nt][r] + bnc[nt]) * unc[nt];
            #pragma unroll
            for (int off = 1; off < 16; off <<= 1)
                v += __shfl_xor(v, off, 16);
            if (c == 0)
                s_lds[rowbase + quad * 4 + r] = expf(v);
        }

        // weight = exp-score of THIS lane's row (same-wave LDS RAW, in-order)
        const float ec = s_lds[rowbase + c];

        // ---- pool phase: re-load granules (L1/L2-hot) into the butterfly.
        // Level-1 pairs are pre[j] / pre[j+8] of R15 == xr[o] / xr[o+32]
        // with o = (j>>1)*8 + quad*2 + (j&1). Same values, same order.
        float4 h8[8];
        #pragma unroll
        for (int j = 0; j < 8; j++) {
            const int o = (j >> 1) * 8 + quad * 2 + (j & 1);
            const float4 a = mul4s(xr[o],      ec);
            const float4 b = mul4s(xr[o + 32], ec);
            h8[j] = add4(sel4((c & 8) != 0, b, a),
                         shflxor4(sel4((c & 8) != 0, a, b), 8));
        }
        float4 h4[4];
        #pragma unroll
        for (int j = 0; j < 4; j++) {
            const float4 a = h4[0], bqq = h4[0];  // placeholder avoided below
            (void)a; (void)bqq;
            const float4 aa = h8[j], bb = h8[j + 4];
            h4[j] = add4(sel4((c & 4) != 0, bb, aa),
                         shflxor4(sel4((c & 4) != 0, aa, bb), 4));
        }
        float4 h2[2];
        #pragma unroll
        for (int j = 0; j < 2; j++) {
            const float4 aa = h4[j], bb = h4[j + 2];
            h2[j] = add4(sel4((c & 2) != 0, bb, aa),
                         shflxor4(sel4((c & 2) != 0, aa, bb), 2));
        }
        {
            const float4 aa = h2[0], bb = h2[1];
            const float4 h1 = add4(sel4((c & 1) != 0, bb, aa),
                                   shflxor4(sel4((c & 1) != 0, aa, bb), 1));
            accp = add4(accp, h1);
        }
    }

    // lane (c,quad) owns granule g -> bijective float4 store, no masking
    const int g = (c >> 1) * 8 + quad * 2 + (c & 1);
    *(float4*)&part[w * 256 + g * 4] = accp;
    __syncthreads();   // all partials + all s_lds scores visible

    // ---- denominator: wave 0 sums the 512 exp-scores ----
    if (tid < 64) {
        float s = 0.0f;
        #pragma unroll
        for (int k = 0; k < 8; k++) s += s_lds[tid + k * 64];
        #pragma unroll
        for (int off = 1; off < 64; off <<= 1) s += __shfl_xor(s, off);
        if (tid == 0) s_inv = 1.0f / (s + EPS);
    }
    __syncthreads();

    // ---- final: sum the 16 wave partials, scale, store ----
    if (tid < 256) {
        float o = 0.0f;
        #pragma unroll
        for (int wv = 0; wv < NW; wv++) o += part[wv * 256 + tid];
        out[(size_t)bb * 256 + tid] = o * s_inv;
    }
}

// ---------------------------------------------------------------------------
extern "C" void kernel_launch(void* const* d_in, const int* in_sizes, int n_in,
                              void* d_out, int out_size, void* d_ws, size_t ws_size,
                              hipStream_t stream)
{
    const float* x = (const float*)d_in[0];
    const float* W = (const float*)d_in[1];
    const float* b = (const float*)d_in[2];
    const float* u = (const float*)d_in[3];

    unsigned short* Wf  = (unsigned short*)d_ws;          // 16384 u16
    float*         bu64 = (float*)(Wf + 16384);           // 128 f
    float*         out  = (float*)d_out;

    prep_kernel  <<<64,  256,  0, stream>>>(W, b, u, Wf, bu64);
    fused_kernel <<<B_,  1024, 0, stream>>>(x, Wf, bu64, out);
}